// Round 1
// baseline (5609.624 us; speedup 1.0000x reference)
//
#include <hip/hip_runtime.h>
#include <math.h>

#define BB 4
#define TT 512
#define SDIM 64
#define ADIM 32
#define HDIM 512
#define NH 8
#define NBLK 6
#define DFF 2048
#define SS 1536          // 3*T
#define DH 64
#define MS (BB*SS)       // 6144 rows
#define KT 32            // K/V tile rows in attention

// ---------------- block layernorm helper (512 threads, 512 cols) ----------------
__device__ __forceinline__ float block_ln_512(float val, float* red, int col,
                                              const float* __restrict__ g,
                                              const float* __restrict__ bvec)
{
    red[col] = val;
    __syncthreads();
    for (int s = 256; s > 0; s >>= 1) {
        if (col < s) red[col] += red[col + s];
        __syncthreads();
    }
    float mean = red[0] * (1.0f / HDIM);
    __syncthreads();
    float d = val - mean;
    red[col] = d * d;
    __syncthreads();
    for (int s = 256; s > 0; s >>= 1) {
        if (col < s) red[col] += red[col + s];
        __syncthreads();
    }
    float var = red[0] * (1.0f / HDIM);
    __syncthreads();
    return d * rsqrtf(var + 1e-5f) * g[col] + bvec[col];
}

// ---------------- embed: x@W + b + te, then LN ----------------
__global__ __launch_bounds__(512) void embed_ln_kernel(
    const int* __restrict__ timesteps,
    const float* __restrict__ state0,
    const float* __restrict__ state1,
    const float* __restrict__ actions,
    const float* __restrict__ time_emb,
    const float* __restrict__ Ws, const float* __restrict__ bs,
    const float* __restrict__ Wa, const float* __restrict__ ba,
    const float* __restrict__ eg, const float* __restrict__ eb,
    float* __restrict__ h)
{
    __shared__ float xs[SDIM];
    __shared__ float red[512];
    int row = blockIdx.x;                 // 0..MS-1
    int b = row / SS;
    int pos = row - b * SS;
    int i = pos / 3;
    int t = pos - i * 3;                  // 0,1,2 (block-uniform)
    int col = threadIdx.x;

    const float* x; const float* W; const float* bias; int K;
    if (t == 0)      { x = state0  + (size_t)(b*TT + i) * SDIM; W = Ws; bias = bs; K = SDIM; }
    else if (t == 1) { x = state1  + (size_t)(b*TT + i) * SDIM; W = Ws; bias = bs; K = SDIM; }
    else             { x = actions + (size_t)(b*TT + i) * ADIM; W = Wa; bias = ba; K = ADIM; }

    if (col < K) xs[col] = x[col];
    __syncthreads();

    int ts = timesteps[b*TT + i];
    float acc = bias[col] + time_emb[(size_t)ts * HDIM + col];
    for (int kk = 0; kk < K; ++kk)
        acc += xs[kk] * W[(size_t)kk * HDIM + col];

    float y = block_ln_512(acc, red, col, eg, eb);
    h[(size_t)row * HDIM + col] = y;
}

// ---------------- residual add + LN: h = LN(h + y) ----------------
__global__ __launch_bounds__(512) void ln_add_kernel(
    float* __restrict__ h, const float* __restrict__ y,
    const float* __restrict__ g, const float* __restrict__ bvec)
{
    __shared__ float red[512];
    int row = blockIdx.x, col = threadIdx.x;
    float val = h[(size_t)row * HDIM + col] + y[(size_t)row * HDIM + col];
    float o = block_ln_512(val, red, col, g, bvec);
    h[(size_t)row * HDIM + col] = o;
}

// ---------------- tiled GEMM: C = A(MxK) @ W(KxN) + bias, optional exact GELU ----------------
__global__ __launch_bounds__(256) void gemm_kernel(
    const float* __restrict__ A, const float* __restrict__ W,
    const float* __restrict__ bias, float* __restrict__ C,
    int M, int N, int K, int act)
{
    __shared__ float Ast[16][68];   // [k][m], pad 68 -> aligned float4 reads, conflict-free
    __shared__ float Bs[16][64];    // [k][n]
    int tid = threadIdx.x;
    int tx = tid & 15, ty = tid >> 4;
    int row0 = blockIdx.y * 64;
    int col0 = blockIdx.x * 64;
    float acc[4][4] = {};

    for (int k0 = 0; k0 < K; k0 += 16) {
        // A tile 64x16: one float4 per thread, store transposed
        int r  = tid >> 2;
        int ca = (tid & 3) * 4;
        float4 av = *(const float4*)(A + (size_t)(row0 + r) * K + k0 + ca);
        Ast[ca+0][r] = av.x; Ast[ca+1][r] = av.y; Ast[ca+2][r] = av.z; Ast[ca+3][r] = av.w;
        // B tile 16x64: one float4 per thread
        int r2 = tid >> 4;
        int cb = (tid & 15) * 4;
        *(float4*)&Bs[r2][cb] = *(const float4*)(W + (size_t)(k0 + r2) * N + col0 + cb);
        __syncthreads();
        #pragma unroll
        for (int kk = 0; kk < 16; ++kk) {
            float4 a4 = *(const float4*)&Ast[kk][ty * 4];
            float4 b4 = *(const float4*)&Bs[kk][tx * 4];
            acc[0][0] += a4.x*b4.x; acc[0][1] += a4.x*b4.y; acc[0][2] += a4.x*b4.z; acc[0][3] += a4.x*b4.w;
            acc[1][0] += a4.y*b4.x; acc[1][1] += a4.y*b4.y; acc[1][2] += a4.y*b4.z; acc[1][3] += a4.y*b4.w;
            acc[2][0] += a4.z*b4.x; acc[2][1] += a4.z*b4.y; acc[2][2] += a4.z*b4.z; acc[2][3] += a4.z*b4.w;
            acc[3][0] += a4.w*b4.x; acc[3][1] += a4.w*b4.y; acc[3][2] += a4.w*b4.z; acc[3][3] += a4.w*b4.w;
        }
        __syncthreads();
    }

    #pragma unroll
    for (int i2 = 0; i2 < 4; ++i2) {
        int rr = row0 + ty * 4 + i2;
        float4 o;
        float* po = &o.x;
        #pragma unroll
        for (int j = 0; j < 4; ++j) {
            int cc = col0 + tx * 4 + j;
            float vv = acc[i2][j] + bias[cc];
            if (act) vv = 0.5f * vv * (1.0f + erff(vv * 0.70710678118654752f));
            po[j] = vv;
        }
        *(float4*)(C + (size_t)rr * N + col0 + tx * 4) = o;
    }
}

// ---------------- fused causal flash attention ----------------
// grid (S/64, NH, B), 256 threads. Q tile 64 rows, K/V tiles 32 rows.
__global__ __launch_bounds__(256) void attn_kernel(
    const float* __restrict__ Qg, const float* __restrict__ Kg,
    const float* __restrict__ Vg, float* __restrict__ Og)
{
    __shared__ float Qs[64][65];
    __shared__ float Ks[KT][65];
    __shared__ float Vs[KT][65];
    __shared__ float Ps[64][33];
    __shared__ float red[4][64];
    __shared__ float mrow[64], lrow[64], arow[64];

    int qt = blockIdx.x, hh = blockIdx.y, b = blockIdx.z;
    int tid = threadIdx.x;
    int tx = tid & 15, ty = tid >> 4;

    // load Q tile (64 x 64)
    for (int l = 0; l < 4; ++l) {
        int idx = tid + l * 256;          // 0..1023
        int r = idx >> 4;
        int c = (idx & 15) * 4;
        float4 vv = *(const float4*)(Qg + ((size_t)(b*SS + qt*64 + r)) * HDIM + hh*DH + c);
        Qs[r][c] = vv.x; Qs[r][c+1] = vv.y; Qs[r][c+2] = vv.z; Qs[r][c+3] = vv.w;
    }
    if (tid < 64) { mrow[tid] = -1e30f; lrow[tid] = 0.0f; }
    float acc[4][4] = {};                 // O acc: rows ty*4+i, cols tx*4+j
    __syncthreads();

    int nkt = (qt + 1) * 2;
    for (int jt = 0; jt < nkt; ++jt) {
        // load K/V tiles (32 x 64 each)
        for (int l = 0; l < 2; ++l) {
            int idx = tid + l * 256;      // 0..511
            int r = idx >> 4;             // 0..31
            int c = (idx & 15) * 4;
            size_t gofs = ((size_t)(b*SS + jt*KT + r)) * HDIM + hh*DH + c;
            float4 kv = *(const float4*)(Kg + gofs);
            Ks[r][c] = kv.x; Ks[r][c+1] = kv.y; Ks[r][c+2] = kv.z; Ks[r][c+3] = kv.w;
            float4 vv = *(const float4*)(Vg + gofs);
            Vs[r][c] = vv.x; Vs[r][c+1] = vv.y; Vs[r][c+2] = vv.z; Vs[r][c+3] = vv.w;
        }
        __syncthreads();

        // Sc = (Q K^T) * scale : rows ty*4+i, cols tx*2+j
        float sc[4][2] = {};
        #pragma unroll 8
        for (int d = 0; d < DH; ++d) {
            float a0 = Qs[ty*4+0][d], a1 = Qs[ty*4+1][d];
            float a2 = Qs[ty*4+2][d], a3 = Qs[ty*4+3][d];
            float k0 = Ks[tx*2+0][d], k1 = Ks[tx*2+1][d];
            sc[0][0] += a0*k0; sc[0][1] += a0*k1;
            sc[1][0] += a1*k0; sc[1][1] += a1*k1;
            sc[2][0] += a2*k0; sc[2][1] += a2*k1;
            sc[3][0] += a3*k0; sc[3][1] += a3*k1;
        }
        int qbase = qt * 64, kbase = jt * KT;
        #pragma unroll
        for (int i2 = 0; i2 < 4; ++i2)
            #pragma unroll
            for (int j = 0; j < 2; ++j) {
                int rg = qbase + ty*4 + i2;
                int cg = kbase + tx*2 + j;
                float vvv = sc[i2][j] * 0.125f;     // 1/sqrt(64)
                if (cg > rg) vvv = -1e30f;
                Ps[ty*4+i2][tx*2+j] = vvv;
            }
        __syncthreads();

        // online softmax row pass: each wave (sub) owns 8 cols of every row
        {
            int rr = tid & 63, sub = tid >> 6;
            float mx = -1e30f;
            #pragma unroll
            for (int c = 0; c < 8; ++c) mx = fmaxf(mx, Ps[rr][sub*8 + c]);
            red[sub][rr] = mx;
            __syncthreads();
            if (sub == 0) {
                float m0 = fmaxf(fmaxf(red[0][rr], red[1][rr]), fmaxf(red[2][rr], red[3][rr]));
                float mold = mrow[rr];
                float mnew = fmaxf(mold, m0);
                mrow[rr] = mnew;
                arow[rr] = __expf(mold - mnew);
            }
            __syncthreads();
            float mnew = mrow[rr];
            float sum = 0.0f;
            #pragma unroll
            for (int c = 0; c < 8; ++c) {
                float p = __expf(Ps[rr][sub*8 + c] - mnew);
                Ps[rr][sub*8 + c] = p;
                sum += p;
            }
            red[sub][rr] = sum;
            __syncthreads();
            if (sub == 0) {
                float s0 = red[0][rr] + red[1][rr] + red[2][rr] + red[3][rr];
                lrow[rr] = lrow[rr] * arow[rr] + s0;
            }
        }
        __syncthreads();

        // O = O*alpha + P @ V
        float al[4];
        #pragma unroll
        for (int i2 = 0; i2 < 4; ++i2) al[i2] = arow[ty*4 + i2];
        #pragma unroll
        for (int i2 = 0; i2 < 4; ++i2)
            #pragma unroll
            for (int j = 0; j < 4; ++j) acc[i2][j] *= al[i2];
        #pragma unroll 8
        for (int kk = 0; kk < KT; ++kk) {
            float p0 = Ps[ty*4+0][kk], p1 = Ps[ty*4+1][kk];
            float p2 = Ps[ty*4+2][kk], p3 = Ps[ty*4+3][kk];
            float v0 = Vs[kk][tx*4+0], v1 = Vs[kk][tx*4+1];
            float v2 = Vs[kk][tx*4+2], v3 = Vs[kk][tx*4+3];
            acc[0][0] += p0*v0; acc[0][1] += p0*v1; acc[0][2] += p0*v2; acc[0][3] += p0*v3;
            acc[1][0] += p1*v0; acc[1][1] += p1*v1; acc[1][2] += p1*v2; acc[1][3] += p1*v3;
            acc[2][0] += p2*v0; acc[2][1] += p2*v1; acc[2][2] += p2*v2; acc[2][3] += p2*v3;
            acc[3][0] += p3*v0; acc[3][1] += p3*v1; acc[3][2] += p3*v2; acc[3][3] += p3*v3;
        }
        __syncthreads();
    }

    #pragma unroll
    for (int i2 = 0; i2 < 4; ++i2) {
        int rr = ty*4 + i2;
        float inv = 1.0f / lrow[rr];
        float4 o;
        o.x = acc[i2][0]*inv; o.y = acc[i2][1]*inv; o.z = acc[i2][2]*inv; o.w = acc[i2][3]*inv;
        *(float4*)(Og + ((size_t)(b*SS + qt*64 + rr)) * HDIM + hh*DH + tx*4) = o;
    }
}

// ---------------- final projection: rows pos%3==1, 512 -> 32 ----------------
__global__ __launch_bounds__(256) void proj_kernel(
    const float* __restrict__ h, const float* __restrict__ Wp,
    const float* __restrict__ bp, float* __restrict__ out)
{
    int rid = blockIdx.x * 8 + (threadIdx.x >> 5);   // 0..B*T-1
    int col = threadIdx.x & 31;
    int b = rid / TT, i = rid - b * TT;
    const float* x = h + ((size_t)(b*SS) + 3*i + 1) * HDIM;
    float acc = bp[col];
    for (int kk = 0; kk < HDIM; ++kk)
        acc += x[kk] * Wp[kk * ADIM + col];
    out[(size_t)rid * ADIM + col] = acc;
}

extern "C" void kernel_launch(void* const* d_in, const int* in_sizes, int n_in,
                              void* d_out, int out_size, void* d_ws, size_t ws_size,
                              hipStream_t stream)
{
    (void)in_sizes; (void)n_in; (void)out_size; (void)ws_size;
    const int*   timesteps = (const int*)  d_in[0];
    const float* state0    = (const float*)d_in[1];
    const float* state1    = (const float*)d_in[2];
    const float* actions   = (const float*)d_in[3];
    const float* time_emb  = (const float*)d_in[4];
    const float* Ws  = (const float*)d_in[5];
    const float* bs  = (const float*)d_in[6];
    const float* Wa  = (const float*)d_in[7];
    const float* ba  = (const float*)d_in[8];
    const float* Wq  = (const float*)d_in[9];
    const float* bq  = (const float*)d_in[10];
    const float* Wk  = (const float*)d_in[11];
    const float* bk  = (const float*)d_in[12];
    const float* Wv  = (const float*)d_in[13];
    const float* bv  = (const float*)d_in[14];
    const float* Wo  = (const float*)d_in[15];
    const float* bo  = (const float*)d_in[16];
    const float* W1  = (const float*)d_in[17];
    const float* b1  = (const float*)d_in[18];
    const float* W2  = (const float*)d_in[19];
    const float* b2  = (const float*)d_in[20];
    const float* ln1g = (const float*)d_in[21];
    const float* ln1b = (const float*)d_in[22];
    const float* ln2g = (const float*)d_in[23];
    const float* ln2b = (const float*)d_in[24];
    const float* elng = (const float*)d_in[25];
    const float* elnb = (const float*)d_in[26];
    const float* Wp   = (const float*)d_in[27];
    const float* bp   = (const float*)d_in[28];
    float* out = (float*)d_out;

    float* wsf = (float*)d_ws;
    const size_t SZ = (size_t)MS * HDIM;
    float* h   = wsf;
    float* q   = h   + SZ;
    float* k   = q   + SZ;
    float* v   = k   + SZ;
    float* ctx = v   + SZ;
    float* tmp = ctx + SZ;
    float* hid = q;           // MLP hidden (MS*DFF) aliases dead q/k/v/ctx

    embed_ln_kernel<<<MS, 512, 0, stream>>>(timesteps, state0, state1, actions, time_emb,
                                            Ws, bs, Wa, ba, elng, elnb, h);

    dim3 gH(HDIM/64, MS/64);      // 8 x 96
    dim3 gF(DFF/64, MS/64);       // 32 x 96
    dim3 gA(SS/64, NH, BB);       // 24 x 8 x 4

    for (int l = 0; l < NBLK; ++l) {
        const float* wq = Wq + (size_t)l * HDIM * HDIM;
        const float* wk = Wk + (size_t)l * HDIM * HDIM;
        const float* wv = Wv + (size_t)l * HDIM * HDIM;
        const float* wo = Wo + (size_t)l * HDIM * HDIM;
        const float* w1 = W1 + (size_t)l * HDIM * DFF;
        const float* w2 = W2 + (size_t)l * DFF * HDIM;

        gemm_kernel<<<gH, 256, 0, stream>>>(h, wq, bq + l*HDIM, q, MS, HDIM, HDIM, 0);
        gemm_kernel<<<gH, 256, 0, stream>>>(h, wk, bk + l*HDIM, k, MS, HDIM, HDIM, 0);
        gemm_kernel<<<gH, 256, 0, stream>>>(h, wv, bv + l*HDIM, v, MS, HDIM, HDIM, 0);
        attn_kernel<<<gA, 256, 0, stream>>>(q, k, v, ctx);
        gemm_kernel<<<gH, 256, 0, stream>>>(ctx, wo, bo + l*HDIM, tmp, MS, HDIM, HDIM, 0);
        ln_add_kernel<<<MS, 512, 0, stream>>>(h, tmp, ln1g + l*HDIM, ln1b + l*HDIM);
        gemm_kernel<<<gF, 256, 0, stream>>>(h, w1, b1 + l*DFF, hid, MS, DFF, HDIM, 1);
        gemm_kernel<<<gH, 256, 0, stream>>>(hid, w2, b2 + l*HDIM, tmp, MS, HDIM, DFF, 0);
        ln_add_kernel<<<MS, 512, 0, stream>>>(h, tmp, ln2g + l*HDIM, ln2b + l*HDIM);
    }

    proj_kernel<<<(BB*TT)/8, 256, 0, stream>>>(h, Wp, bp, out);
}

// Round 2
// 1725.239 us; speedup vs baseline: 3.2515x; 3.2515x over previous
//
#include <hip/hip_runtime.h>
#include <hip/hip_bf16.h>
#include <math.h>

#define BB 4
#define TT 512
#define SDIM 64
#define ADIM 32
#define HDIM 512
#define NH 8
#define NBLK 6
#define DFF 2048
#define SS 1536          // 3*T
#define DH 64
#define MS (BB*SS)       // 6144 rows

typedef __attribute__((ext_vector_type(8))) __bf16 bf16x8;
typedef __attribute__((ext_vector_type(4))) float f32x4;

__device__ __forceinline__ __bf16 f2b(float x) { return (__bf16)x; }

// ================= shuffle-based LN over 512 threads =================
__device__ __forceinline__ float block_ln2(float val, int tid,
                                           const float* __restrict__ g,
                                           const float* __restrict__ bvec,
                                           float* red)
{
    float s = val, sq = val * val;
    #pragma unroll
    for (int off = 32; off; off >>= 1) { s += __shfl_xor(s, off); sq += __shfl_xor(sq, off); }
    int w = tid >> 6;
    if ((tid & 63) == 0) { red[w] = s; red[8 + w] = sq; }
    __syncthreads();
    float S = 0.f, SQ = 0.f;
    #pragma unroll
    for (int i = 0; i < 8; ++i) { S += red[i]; SQ += red[8 + i]; }
    float mean = S * (1.f / HDIM);
    float var  = SQ * (1.f / HDIM) - mean * mean;
    return (val - mean) * rsqrtf(var + 1e-5f) * g[tid] + bvec[tid];
}

// ================= embed + LN -> h (fp32) and h_bf (bf16) =================
__global__ __launch_bounds__(512) void embed_ln_kernel(
    const int* __restrict__ timesteps,
    const float* __restrict__ state0, const float* __restrict__ state1,
    const float* __restrict__ actions, const float* __restrict__ time_emb,
    const float* __restrict__ Ws, const float* __restrict__ bs,
    const float* __restrict__ Wa, const float* __restrict__ ba,
    const float* __restrict__ eg, const float* __restrict__ eb,
    float* __restrict__ h, __bf16* __restrict__ h_bf)
{
    __shared__ float xs[SDIM];
    __shared__ float red[16];
    int row = blockIdx.x;
    int b = row / SS;
    int pos = row - b * SS;
    int i = pos / 3;
    int t = pos - i * 3;
    int col = threadIdx.x;

    const float* x; const float* W; const float* bias; int K;
    if (t == 0)      { x = state0  + (size_t)(b*TT + i) * SDIM; W = Ws; bias = bs; K = SDIM; }
    else if (t == 1) { x = state1  + (size_t)(b*TT + i) * SDIM; W = Ws; bias = bs; K = SDIM; }
    else             { x = actions + (size_t)(b*TT + i) * ADIM; W = Wa; bias = ba; K = ADIM; }

    if (col < K) xs[col] = x[col];
    __syncthreads();

    int ts = timesteps[b*TT + i];
    float acc = bias[col] + time_emb[(size_t)ts * HDIM + col];
    for (int kk = 0; kk < K; ++kk)
        acc += xs[kk] * W[(size_t)kk * HDIM + col];

    float y = block_ln2(acc, col, eg, eb, red);
    h[(size_t)row * HDIM + col] = y;
    h_bf[(size_t)row * HDIM + col] = f2b(y);
}

// ================= residual add + LN =================
__global__ __launch_bounds__(512) void ln_add_kernel(
    float* __restrict__ h, const float* __restrict__ y,
    const float* __restrict__ g, const float* __restrict__ bvec,
    __bf16* __restrict__ h_bf)
{
    __shared__ float red[16];
    int row = blockIdx.x, col = threadIdx.x;
    float val = h[(size_t)row * HDIM + col] + y[(size_t)row * HDIM + col];
    float o = block_ln2(val, col, g, bvec, red);
    h[(size_t)row * HDIM + col] = o;
    h_bf[(size_t)row * HDIM + col] = f2b(o);
}

// ================= weight pack: fp32 [K][N] -> bf16 [N][K] =================
__global__ __launch_bounds__(256) void pack_kernel(
    const float* __restrict__ wq, const float* __restrict__ wk,
    const float* __restrict__ wv, const float* __restrict__ wo,
    const float* __restrict__ w1, const float* __restrict__ w2,
    const float* __restrict__ bq_, const float* __restrict__ bk_, const float* __restrict__ bv_,
    __bf16* __restrict__ wqkvT, __bf16* __restrict__ woT,
    __bf16* __restrict__ w1T, __bf16* __restrict__ w2T, float* __restrict__ biasq)
{
    int bid = blockIdx.x;
    int tid = threadIdx.x;
    if (bid == 768) {
        for (int i = tid; i < 1536; i += 256)
            biasq[i] = (i < 512) ? bq_[i] : ((i < 1024) ? bk_[i-512] : bv_[i-1024]);
        return;
    }
    __shared__ float Ls[64][65];
    const float* src; __bf16* dst; int K, N, kt, nt;
    if (bid < 192) {
        int sec = bid / 64, t = bid % 64;
        src = (sec == 0) ? wq : (sec == 1) ? wk : wv;
        dst = wqkvT + (size_t)sec * 512 * 512;
        K = 512; N = 512; nt = t >> 3; kt = t & 7;
    } else if (bid < 256) {
        int t = bid - 192; src = wo; dst = woT; K = 512; N = 512; nt = t >> 3; kt = t & 7;
    } else if (bid < 512) {
        int t = bid - 256; src = w1; dst = w1T; K = 512; N = 2048; nt = t >> 3; kt = t & 7;
    } else {
        int t = bid - 512; src = w2; dst = w2T; K = 2048; N = 512; nt = t & 7; kt = t >> 3;
    }
    int k0 = kt * 64, n0 = nt * 64;
    int rr = tid >> 4, cc = (tid & 15) * 4;
    #pragma unroll
    for (int p = 0; p < 4; ++p) {
        float4 v = *(const float4*)(src + (size_t)(k0 + rr + p*16) * N + n0 + cc);
        Ls[rr + p*16][cc] = v.x; Ls[rr + p*16][cc+1] = v.y;
        Ls[rr + p*16][cc+2] = v.z; Ls[rr + p*16][cc+3] = v.w;
    }
    __syncthreads();
    int nn = tid >> 3, kc = (tid & 7) * 8;
    #pragma unroll
    for (int p = 0; p < 2; ++p) {
        __bf16 t8[8];
        #pragma unroll
        for (int t2 = 0; t2 < 8; ++t2) t8[t2] = f2b(Ls[kc + t2][nn + p*32]);
        *(uint4*)(dst + (size_t)(n0 + nn + p*32) * K + k0 + kc) = *(uint4*)t8;
    }
}

// ================= V transpose: qkv v-section -> VT[(b*NH+h)*64+d][s] =================
__global__ __launch_bounds__(256) void vtrans_kernel(
    const __bf16* __restrict__ qkv, __bf16* __restrict__ VT)
{
    __shared__ __bf16 Ls[64][72];
    int dt = blockIdx.x;          // 0..7 (head)
    int st = blockIdx.y;          // 0..95
    int s0 = st * 64;
    int b  = s0 / SS;
    int srel = s0 - b * SS;
    int tid = threadIdx.x;
    int r = tid >> 3, ch = tid & 7;
    #pragma unroll
    for (int p = 0; p < 2; ++p) {
        uint4 v = *(const uint4*)(qkv + (size_t)(s0 + r + p*32) * 1536 + 1024 + dt*64 + ch*8);
        *(uint4*)&Ls[r + p*32][ch*8] = v;
    }
    __syncthreads();
    int dd = tid >> 3;
    #pragma unroll
    for (int p = 0; p < 2; ++p) {
        __bf16 t8[8];
        #pragma unroll
        for (int t2 = 0; t2 < 8; ++t2) t8[t2] = Ls[ch*8 + t2][dd + p*32];
        *(uint4*)(VT + ((size_t)(b*NH + dt) * 64 + dd + p*32) * SS + srel + ch*8) = *(uint4*)t8;
    }
}

// ================= bf16 MFMA GEMM: C = A(MxK) @ Bt^T + bias =================
// A: bf16 row-major MxK.  Bt: bf16 [N][K].  flags: 1 = bf16 out, 2 = gelu.
__global__ __launch_bounds__(256) void gemm_mfma(
    const __bf16* __restrict__ A, const __bf16* __restrict__ Bt,
    const float* __restrict__ bias, void* __restrict__ Cout,
    int M, int N, int K, int flags)
{
    __shared__ __bf16 As[128][40];
    __shared__ __bf16 Bs[128][40];
    int tid = threadIdx.x;
    int wave = tid >> 6, lane = tid & 63;
    int l15 = lane & 15, quad = lane >> 4;
    int wy = wave >> 1, wx = wave & 1;
    int m0 = blockIdx.y * 128, n0 = blockIdx.x * 128;

    f32x4 acc[4][4];
    #pragma unroll
    for (int i = 0; i < 4; ++i)
        #pragma unroll
        for (int j = 0; j < 4; ++j) acc[i][j] = (f32x4){0.f,0.f,0.f,0.f};

    int srow = tid >> 2, schunk = (tid & 3) * 8;
    for (int k0 = 0; k0 < K; k0 += 32) {
        uint4 a0 = *(const uint4*)(A  + (size_t)(m0 + srow)      * K + k0 + schunk);
        uint4 a1 = *(const uint4*)(A  + (size_t)(m0 + srow + 64) * K + k0 + schunk);
        uint4 b0 = *(const uint4*)(Bt + (size_t)(n0 + srow)      * K + k0 + schunk);
        uint4 b1 = *(const uint4*)(Bt + (size_t)(n0 + srow + 64) * K + k0 + schunk);
        __syncthreads();
        *(uint4*)&As[srow     ][schunk] = a0;
        *(uint4*)&As[srow + 64][schunk] = a1;
        *(uint4*)&Bs[srow     ][schunk] = b0;
        *(uint4*)&Bs[srow + 64][schunk] = b1;
        __syncthreads();
        bf16x8 af[4], bf[4];
        #pragma unroll
        for (int i = 0; i < 4; ++i) af[i] = *(const bf16x8*)&As[wy*64 + i*16 + l15][quad*8];
        #pragma unroll
        for (int j = 0; j < 4; ++j) bf[j] = *(const bf16x8*)&Bs[wx*64 + j*16 + l15][quad*8];
        #pragma unroll
        for (int i = 0; i < 4; ++i)
            #pragma unroll
            for (int j = 0; j < 4; ++j)
                acc[i][j] = __builtin_amdgcn_mfma_f32_16x16x32_bf16(af[i], bf[j], acc[i][j], 0, 0, 0);
    }

    float* Cf = (float*)Cout;
    __bf16* Cb = (__bf16*)Cout;
    int obf = flags & 1, gel = flags & 2;
    #pragma unroll
    for (int j = 0; j < 4; ++j) {
        int cc = n0 + wx*64 + j*16 + l15;
        float bv = bias[cc];
        #pragma unroll
        for (int i = 0; i < 4; ++i) {
            #pragma unroll
            for (int r = 0; r < 4; ++r) {
                int rr = m0 + wy*64 + i*16 + quad*4 + r;
                float v = acc[i][j][r] + bv;
                if (gel) v = 0.5f * v * (1.f + erff(v * 0.70710678118654752f));
                if (obf) Cb[(size_t)rr * N + cc] = f2b(v);
                else     Cf[(size_t)rr * N + cc] = v;
            }
        }
    }
}

// ================= MFMA flash attention =================
// qkv: [B*S][1536] bf16 (q|k|v).  VT: [(b*NH+h)*64 + d][S] bf16.  ctx: [B*S][512] bf16.
__global__ __launch_bounds__(256) void attn_kernel(
    const __bf16* __restrict__ qkv, const __bf16* __restrict__ VT,
    __bf16* __restrict__ ctx)
{
    __shared__ __bf16 Ps[4][16][40];
    int qt = blockIdx.x, h = blockIdx.y, b = blockIdx.z;
    int tid = threadIdx.x;
    int w = tid >> 6, lane = tid & 63;
    int l15 = lane & 15, quad = lane >> 4;
    int qbase = qt * 64 + w * 16;

    const __bf16* qrow = qkv + (size_t)(b*SS + qbase + l15) * 1536 + h*64 + quad*8;
    bf16x8 af0 = *(const bf16x8*)qrow;
    bf16x8 af1 = *(const bf16x8*)(qrow + 32);

    f32x4 o0 = {0.f,0.f,0.f,0.f}, o1 = o0, o2 = o0, o3 = o0;
    float m[4] = {-1e30f,-1e30f,-1e30f,-1e30f};
    float l[4] = {0.f,0.f,0.f,0.f};

    const __bf16* kp = qkv + (size_t)(b*SS) * 1536 + 512 + h*64 + quad*8;
    const __bf16* vp = VT + (size_t)(b*NH + h) * 64 * SS + quad*8;
    __bf16* ps = &Ps[w][0][0];

    int nkt = 2*qt + 1 + (w >> 1);
    for (int jt = 0; jt < nkt; ++jt) {
        int kb = jt * 32;
        bf16x8 kf00 = *(const bf16x8*)(kp + (size_t)(kb + l15) * 1536);
        bf16x8 kf01 = *(const bf16x8*)(kp + (size_t)(kb + l15) * 1536 + 32);
        bf16x8 kf10 = *(const bf16x8*)(kp + (size_t)(kb + 16 + l15) * 1536);
        bf16x8 kf11 = *(const bf16x8*)(kp + (size_t)(kb + 16 + l15) * 1536 + 32);
        f32x4 s0 = {0.f,0.f,0.f,0.f}, s1 = {0.f,0.f,0.f,0.f};
        s0 = __builtin_amdgcn_mfma_f32_16x16x32_bf16(af0, kf00, s0, 0, 0, 0);
        s0 = __builtin_amdgcn_mfma_f32_16x16x32_bf16(af1, kf01, s0, 0, 0, 0);
        s1 = __builtin_amdgcn_mfma_f32_16x16x32_bf16(af0, kf10, s1, 0, 0, 0);
        s1 = __builtin_amdgcn_mfma_f32_16x16x32_bf16(af1, kf11, s1, 0, 0, 0);

        int k0i = kb + l15, k1i = kb + 16 + l15;
        #pragma unroll
        for (int r = 0; r < 4; ++r) {
            int q = qbase + quad*4 + r;
            float x0 = (k0i <= q) ? s0[r] * 0.125f : -1e30f;
            float x1 = (k1i <= q) ? s1[r] * 0.125f : -1e30f;
            float tm = fmaxf(x0, x1);
            #pragma unroll
            for (int off = 1; off < 16; off <<= 1) tm = fmaxf(tm, __shfl_xor(tm, off));
            float mnew = fmaxf(m[r], tm);
            float alpha = __expf(m[r] - mnew);
            float p0 = (k0i <= q) ? __expf(x0 - mnew) : 0.f;
            float p1 = (k1i <= q) ? __expf(x1 - mnew) : 0.f;
            float rs = p0 + p1;
            #pragma unroll
            for (int off = 1; off < 16; off <<= 1) rs += __shfl_xor(rs, off);
            l[r] = l[r] * alpha + rs;
            m[r] = mnew;
            o0[r] *= alpha; o1[r] *= alpha; o2[r] *= alpha; o3[r] *= alpha;
            ps[(quad*4 + r) * 40 + l15]      = f2b(p0);
            ps[(quad*4 + r) * 40 + 16 + l15] = f2b(p1);
        }
        asm volatile("s_waitcnt lgkmcnt(0)" ::: "memory");
        bf16x8 pa = *(const bf16x8*)(ps + l15 * 40 + quad*8);
        bf16x8 v0 = *(const bf16x8*)(vp + (size_t)(0*16 + l15) * SS + kb);
        bf16x8 v1 = *(const bf16x8*)(vp + (size_t)(1*16 + l15) * SS + kb);
        bf16x8 v2 = *(const bf16x8*)(vp + (size_t)(2*16 + l15) * SS + kb);
        bf16x8 v3 = *(const bf16x8*)(vp + (size_t)(3*16 + l15) * SS + kb);
        o0 = __builtin_amdgcn_mfma_f32_16x16x32_bf16(pa, v0, o0, 0, 0, 0);
        o1 = __builtin_amdgcn_mfma_f32_16x16x32_bf16(pa, v1, o1, 0, 0, 0);
        o2 = __builtin_amdgcn_mfma_f32_16x16x32_bf16(pa, v2, o2, 0, 0, 0);
        o3 = __builtin_amdgcn_mfma_f32_16x16x32_bf16(pa, v3, o3, 0, 0, 0);
    }

    #pragma unroll
    for (int r = 0; r < 4; ++r) {
        float inv = 1.f / l[r];
        int q = qbase + quad*4 + r;
        __bf16* cp = ctx + (size_t)(b*SS + q) * 512 + h*64 + l15;
        cp[0]  = f2b(o0[r] * inv);
        cp[16] = f2b(o1[r] * inv);
        cp[32] = f2b(o2[r] * inv);
        cp[48] = f2b(o3[r] * inv);
    }
}

// ================= final projection =================
__global__ __launch_bounds__(256) void proj_kernel(
    const float* __restrict__ h, const float* __restrict__ Wp,
    const float* __restrict__ bp, float* __restrict__ out)
{
    int rid = blockIdx.x * 8 + (threadIdx.x >> 5);
    int col = threadIdx.x & 31;
    int b = rid / TT, i = rid - b * TT;
    const float* x = h + ((size_t)(b*SS) + 3*i + 1) * HDIM;
    float acc = bp[col];
    for (int kk = 0; kk < HDIM; ++kk)
        acc += x[kk] * Wp[kk * ADIM + col];
    out[(size_t)rid * ADIM + col] = acc;
}

extern "C" void kernel_launch(void* const* d_in, const int* in_sizes, int n_in,
                              void* d_out, int out_size, void* d_ws, size_t ws_size,
                              hipStream_t stream)
{
    (void)in_sizes; (void)n_in; (void)out_size; (void)ws_size;
    const int*   timesteps = (const int*)  d_in[0];
    const float* state0    = (const float*)d_in[1];
    const float* state1    = (const float*)d_in[2];
    const float* actions   = (const float*)d_in[3];
    const float* time_emb  = (const float*)d_in[4];
    const float* Ws  = (const float*)d_in[5];
    const float* bs  = (const float*)d_in[6];
    const float* Wa  = (const float*)d_in[7];
    const float* ba  = (const float*)d_in[8];
    const float* Wq  = (const float*)d_in[9];
    const float* bq  = (const float*)d_in[10];
    const float* Wk  = (const float*)d_in[11];
    const float* bk  = (const float*)d_in[12];
    const float* Wv  = (const float*)d_in[13];
    const float* bv  = (const float*)d_in[14];
    const float* Wo  = (const float*)d_in[15];
    const float* bo  = (const float*)d_in[16];
    const float* W1  = (const float*)d_in[17];
    const float* b1  = (const float*)d_in[18];
    const float* W2  = (const float*)d_in[19];
    const float* b2  = (const float*)d_in[20];
    const float* ln1g = (const float*)d_in[21];
    const float* ln1b = (const float*)d_in[22];
    const float* ln2g = (const float*)d_in[23];
    const float* ln2b = (const float*)d_in[24];
    const float* elng = (const float*)d_in[25];
    const float* elnb = (const float*)d_in[26];
    const float* Wp   = (const float*)d_in[27];
    const float* bp   = (const float*)d_in[28];
    float* out = (float*)d_out;

    const size_t SZ = (size_t)MS * HDIM;          // 3,145,728
    char* p = (char*)d_ws;
    float*  h    = (float*)p;            p += SZ * 4;
    float*  tmp  = (float*)p;            p += SZ * 4;
    __bf16* h_bf = (__bf16*)p;           p += SZ * 2;
    __bf16* qkv  = (__bf16*)p;           p += SZ * 3 * 2;
    __bf16* ctx  = (__bf16*)p;           p += SZ * 2;
    __bf16* VT   = (__bf16*)p;           p += SZ * 2;
    __bf16* wqkvT = (__bf16*)p;          p += (size_t)1536 * 512 * 2;
    __bf16* woT   = (__bf16*)p;          p += (size_t)512 * 512 * 2;
    __bf16* w1T   = (__bf16*)p;          p += (size_t)2048 * 512 * 2;
    __bf16* w2T   = (__bf16*)p;          p += (size_t)512 * 2048 * 2;
    float*  biasq = (float*)p;           p += 1536 * 4;
    __bf16* hid  = qkv;                  // MS x DFF bf16, aliases qkv+ctx

    embed_ln_kernel<<<MS, 512, 0, stream>>>(timesteps, state0, state1, actions, time_emb,
                                            Ws, bs, Wa, ba, elng, elnb, h, h_bf);

    dim3 gQKV(1536/128, MS/128);   // 12 x 48
    dim3 gO  (512/128,  MS/128);   // 4 x 48
    dim3 gF1 (2048/128, MS/128);   // 16 x 48
    dim3 gA  (SS/64, NH, BB);      // 24 x 8 x 4
    dim3 gV  (NH, MS/64);          // 8 x 96

    for (int lyr = 0; lyr < NBLK; ++lyr) {
        const float* wq = Wq + (size_t)lyr * HDIM * HDIM;
        const float* wk = Wk + (size_t)lyr * HDIM * HDIM;
        const float* wv = Wv + (size_t)lyr * HDIM * HDIM;
        const float* wo = Wo + (size_t)lyr * HDIM * HDIM;
        const float* w1 = W1 + (size_t)lyr * HDIM * DFF;
        const float* w2 = W2 + (size_t)lyr * DFF * HDIM;

        pack_kernel<<<769, 256, 0, stream>>>(wq, wk, wv, wo, w1, w2,
                                             bq + lyr*HDIM, bk + lyr*HDIM, bv + lyr*HDIM,
                                             wqkvT, woT, w1T, w2T, biasq);
        gemm_mfma<<<gQKV, 256, 0, stream>>>(h_bf, wqkvT, biasq, qkv, MS, 1536, HDIM, 1);
        vtrans_kernel<<<gV, 256, 0, stream>>>(qkv, VT);
        attn_kernel<<<gA, 256, 0, stream>>>(qkv, VT, ctx);
        gemm_mfma<<<gO, 256, 0, stream>>>(ctx, woT, bo + lyr*HDIM, tmp, MS, HDIM, HDIM, 0);
        ln_add_kernel<<<MS, 512, 0, stream>>>(h, tmp, ln1g + lyr*HDIM, ln1b + lyr*HDIM, h_bf);
        gemm_mfma<<<gF1, 256, 0, stream>>>(h_bf, w1T, b1 + lyr*DFF, hid, MS, DFF, HDIM, 1 | 2);
        gemm_mfma<<<gO, 256, 0, stream>>>(hid, w2T, b2 + lyr*HDIM, tmp, MS, HDIM, DFF, 0);
        ln_add_kernel<<<MS, 512, 0, stream>>>(h, tmp, ln2g + lyr*HDIM, ln2b + lyr*HDIM, h_bf);
    }

    proj_kernel<<<(BB*TT)/8, 256, 0, stream>>>(h, Wp, bp, out);
}

// Round 4
// 1592.482 us; speedup vs baseline: 3.5226x; 1.0834x over previous
//
#include <hip/hip_runtime.h>
#include <hip/hip_bf16.h>
#include <math.h>

#define BB 4
#define TT 512
#define SDIM 64
#define ADIM 32
#define HDIM 512
#define NH 8
#define NBLK 6
#define DFF 2048
#define SS 1536          // 3*T
#define DH 64
#define MS (BB*SS)       // 6144 rows

typedef __attribute__((ext_vector_type(8))) __bf16 bf16x8;
typedef __attribute__((ext_vector_type(4))) float f32x4;

__device__ __forceinline__ __bf16 f2b(float x) { return (__bf16)x; }

// ================= shuffle-based LN over 512 threads =================
__device__ __forceinline__ float block_ln2(float val, int tid,
                                           const float* __restrict__ g,
                                           const float* __restrict__ bvec,
                                           float* red)
{
    float s = val, sq = val * val;
    #pragma unroll
    for (int off = 32; off; off >>= 1) { s += __shfl_xor(s, off); sq += __shfl_xor(sq, off); }
    int w = tid >> 6;
    if ((tid & 63) == 0) { red[w] = s; red[8 + w] = sq; }
    __syncthreads();
    float S = 0.f, SQ = 0.f;
    #pragma unroll
    for (int i = 0; i < 8; ++i) { S += red[i]; SQ += red[8 + i]; }
    float mean = S * (1.f / HDIM);
    float var  = SQ * (1.f / HDIM) - mean * mean;
    return (val - mean) * rsqrtf(var + 1e-5f) * g[tid] + bvec[tid];
}

// ================= embed + LN -> h (fp32) and h_bf (bf16) =================
__global__ __launch_bounds__(512) void embed_ln_kernel(
    const int* __restrict__ timesteps,
    const float* __restrict__ state0, const float* __restrict__ state1,
    const float* __restrict__ actions, const float* __restrict__ time_emb,
    const float* __restrict__ Ws, const float* __restrict__ bs,
    const float* __restrict__ Wa, const float* __restrict__ ba,
    const float* __restrict__ eg, const float* __restrict__ eb,
    float* __restrict__ h, __bf16* __restrict__ h_bf)
{
    __shared__ float xs[SDIM];
    __shared__ float red[16];
    int row = blockIdx.x;
    int b = row / SS;
    int pos = row - b * SS;
    int i = pos / 3;
    int t = pos - i * 3;
    int col = threadIdx.x;

    const float* x; const float* W; const float* bias; int K;
    if (t == 0)      { x = state0  + (size_t)(b*TT + i) * SDIM; W = Ws; bias = bs; K = SDIM; }
    else if (t == 1) { x = state1  + (size_t)(b*TT + i) * SDIM; W = Ws; bias = bs; K = SDIM; }
    else             { x = actions + (size_t)(b*TT + i) * ADIM; W = Wa; bias = ba; K = ADIM; }

    if (col < K) xs[col] = x[col];
    __syncthreads();

    int ts = timesteps[b*TT + i];
    float acc = bias[col] + time_emb[(size_t)ts * HDIM + col];
    for (int kk = 0; kk < K; ++kk)
        acc += xs[kk] * W[(size_t)kk * HDIM + col];

    float y = block_ln2(acc, col, eg, eb, red);
    h[(size_t)row * HDIM + col] = y;
    h_bf[(size_t)row * HDIM + col] = f2b(y);
}

// ================= residual add + LN =================
__global__ __launch_bounds__(512) void ln_add_kernel(
    float* __restrict__ h, const float* __restrict__ y,
    const float* __restrict__ g, const float* __restrict__ bvec,
    __bf16* __restrict__ h_bf)
{
    __shared__ float red[16];
    int row = blockIdx.x, col = threadIdx.x;
    float val = h[(size_t)row * HDIM + col] + y[(size_t)row * HDIM + col];
    float o = block_ln2(val, col, g, bvec, red);
    h[(size_t)row * HDIM + col] = o;
    h_bf[(size_t)row * HDIM + col] = f2b(o);
}

// ================= weight pack: fp32 [K][N] -> bf16 [N][K] =================
__global__ __launch_bounds__(256) void pack_kernel(
    const float* __restrict__ wq, const float* __restrict__ wk,
    const float* __restrict__ wv, const float* __restrict__ wo,
    const float* __restrict__ w1, const float* __restrict__ w2,
    const float* __restrict__ bq_, const float* __restrict__ bk_, const float* __restrict__ bv_,
    __bf16* __restrict__ wqkvT, __bf16* __restrict__ woT,
    __bf16* __restrict__ w1T, __bf16* __restrict__ w2T, float* __restrict__ biasq)
{
    int bid = blockIdx.x;
    int tid = threadIdx.x;
    if (bid == 768) {
        for (int i = tid; i < 1536; i += 256)
            biasq[i] = (i < 512) ? bq_[i] : ((i < 1024) ? bk_[i-512] : bv_[i-1024]);
        return;
    }
    __shared__ float Ls[64][65];
    const float* src; __bf16* dst; int K, N, kt, nt;
    if (bid < 192) {
        int sec = bid / 64, t = bid % 64;
        src = (sec == 0) ? wq : (sec == 1) ? wk : wv;
        dst = wqkvT + (size_t)sec * 512 * 512;
        K = 512; N = 512; nt = t >> 3; kt = t & 7;
    } else if (bid < 256) {
        int t = bid - 192; src = wo; dst = woT; K = 512; N = 512; nt = t >> 3; kt = t & 7;
    } else if (bid < 512) {
        int t = bid - 256; src = w1; dst = w1T; K = 512; N = 2048; nt = t >> 3; kt = t & 7;
    } else {
        int t = bid - 512; src = w2; dst = w2T; K = 2048; N = 512; nt = t & 7; kt = t >> 3;
    }
    int k0 = kt * 64, n0 = nt * 64;
    int rr = tid >> 4, cc = (tid & 15) * 4;
    #pragma unroll
    for (int p = 0; p < 4; ++p) {
        float4 v = *(const float4*)(src + (size_t)(k0 + rr + p*16) * N + n0 + cc);
        Ls[rr + p*16][cc] = v.x; Ls[rr + p*16][cc+1] = v.y;
        Ls[rr + p*16][cc+2] = v.z; Ls[rr + p*16][cc+3] = v.w;
    }
    __syncthreads();
    int nn = tid >> 3, kc = (tid & 7) * 8;
    #pragma unroll
    for (int p = 0; p < 2; ++p) {
        __bf16 t8[8];
        #pragma unroll
        for (int t2 = 0; t2 < 8; ++t2) t8[t2] = f2b(Ls[kc + t2][nn + p*32]);
        *(uint4*)(dst + (size_t)(n0 + nn + p*32) * K + k0 + kc) = *(uint4*)t8;
    }
}

// ================= V transpose: qkv v-section -> VT[(b*NH+h)*64+d][s] =================
__global__ __launch_bounds__(256) void vtrans_kernel(
    const __bf16* __restrict__ qkv, __bf16* __restrict__ VT)
{
    __shared__ __bf16 Ls[64][72];
    int dt = blockIdx.x;          // 0..7 (head)
    int st = blockIdx.y;          // 0..95
    int s0 = st * 64;
    int b  = s0 / SS;
    int srel = s0 - b * SS;
    int tid = threadIdx.x;
    int r = tid >> 3, ch = tid & 7;
    #pragma unroll
    for (int p = 0; p < 2; ++p) {
        uint4 v = *(const uint4*)(qkv + (size_t)(s0 + r + p*32) * 1536 + 1024 + dt*64 + ch*8);
        *(uint4*)&Ls[r + p*32][ch*8] = v;
    }
    __syncthreads();
    int dd = tid >> 3;
    #pragma unroll
    for (int p = 0; p < 2; ++p) {
        __bf16 t8[8];
        #pragma unroll
        for (int t2 = 0; t2 < 8; ++t2) t8[t2] = Ls[ch*8 + t2][dd + p*32];
        *(uint4*)(VT + ((size_t)(b*NH + dt) * 64 + dd + p*32) * SS + srel + ch*8) = *(uint4*)t8;
    }
}

// ================= bf16 MFMA GEMM: C = A(MxK) @ Bt^T + bias =================
// A: bf16 row-major MxK.  Bt: bf16 [N][K].  flags: 1 = bf16 out, 2 = gelu.
__global__ __launch_bounds__(256) void gemm_mfma(
    const __bf16* __restrict__ A, const __bf16* __restrict__ Bt,
    const float* __restrict__ bias, void* __restrict__ Cout,
    int M, int N, int K, int flags)
{
    __shared__ __bf16 As[128][40];
    __shared__ __bf16 Bs[128][40];
    int tid = threadIdx.x;
    int wave = tid >> 6, lane = tid & 63;
    int l15 = lane & 15, quad = lane >> 4;
    int wy = wave >> 1, wx = wave & 1;
    int m0 = blockIdx.y * 128, n0 = blockIdx.x * 128;

    f32x4 acc[4][4];
    #pragma unroll
    for (int i = 0; i < 4; ++i)
        #pragma unroll
        for (int j = 0; j < 4; ++j) acc[i][j] = (f32x4){0.f,0.f,0.f,0.f};

    int srow = tid >> 2, schunk = (tid & 3) * 8;
    for (int k0 = 0; k0 < K; k0 += 32) {
        uint4 a0 = *(const uint4*)(A  + (size_t)(m0 + srow)      * K + k0 + schunk);
        uint4 a1 = *(const uint4*)(A  + (size_t)(m0 + srow + 64) * K + k0 + schunk);
        uint4 b0 = *(const uint4*)(Bt + (size_t)(n0 + srow)      * K + k0 + schunk);
        uint4 b1 = *(const uint4*)(Bt + (size_t)(n0 + srow + 64) * K + k0 + schunk);
        __syncthreads();
        *(uint4*)&As[srow     ][schunk] = a0;
        *(uint4*)&As[srow + 64][schunk] = a1;
        *(uint4*)&Bs[srow     ][schunk] = b0;
        *(uint4*)&Bs[srow + 64][schunk] = b1;
        __syncthreads();
        bf16x8 af[4], bf[4];
        #pragma unroll
        for (int i = 0; i < 4; ++i) af[i] = *(const bf16x8*)&As[wy*64 + i*16 + l15][quad*8];
        #pragma unroll
        for (int j = 0; j < 4; ++j) bf[j] = *(const bf16x8*)&Bs[wx*64 + j*16 + l15][quad*8];
        #pragma unroll
        for (int i = 0; i < 4; ++i)
            #pragma unroll
            for (int j = 0; j < 4; ++j)
                acc[i][j] = __builtin_amdgcn_mfma_f32_16x16x32_bf16(af[i], bf[j], acc[i][j], 0, 0, 0);
    }

    float* Cf = (float*)Cout;
    __bf16* Cb = (__bf16*)Cout;
    int obf = flags & 1, gel = flags & 2;
    #pragma unroll
    for (int j = 0; j < 4; ++j) {
        int cc = n0 + wx*64 + j*16 + l15;
        float bv = bias[cc];
        #pragma unroll
        for (int i = 0; i < 4; ++i) {
            #pragma unroll
            for (int r = 0; r < 4; ++r) {
                int rr = m0 + wy*64 + i*16 + quad*4 + r;
                float v = acc[i][j][r] + bv;
                if (gel) v = 0.5f * v * (1.f + erff(v * 0.70710678118654752f));
                if (obf) Cb[(size_t)rr * N + cc] = f2b(v);
                else     Cf[(size_t)rr * N + cc] = v;
            }
        }
    }
}

// ================= S^T-layout MFMA flash attention (reg-resident softmax) =================
#define SM_C 0.18033688011112042f   // (1/8) * log2(e)

struct KVfrags { bf16x8 k00, k01, k10, k11, v0, v1, v2, v3; };

__device__ __forceinline__ KVfrags load_kv(const __bf16* kp, const __bf16* vp, int kb)
{
    KVfrags f;
    f.k00 = *(const bf16x8*)(kp + (size_t)kb * 1536);
    f.k01 = *(const bf16x8*)(kp + (size_t)kb * 1536 + 32);
    f.k10 = *(const bf16x8*)(kp + (size_t)(kb + 16) * 1536);
    f.k11 = *(const bf16x8*)(kp + (size_t)(kb + 16) * 1536 + 32);
    f.v0  = *(const bf16x8*)(vp + kb);
    f.v1  = *(const bf16x8*)(vp + (size_t)16 * SS + kb);
    f.v2  = *(const bf16x8*)(vp + (size_t)32 * SS + kb);
    f.v3  = *(const bf16x8*)(vp + (size_t)48 * SS + kb);
    return f;
}

__device__ __forceinline__ unsigned pack2bf(float a, float b)
{
    union { __bf16 h[2]; unsigned u; } t;
    t.h[0] = (__bf16)a; t.h[1] = (__bf16)b;
    return t.u;
}

struct AttnState {
    f32x4 o0, o1, o2, o3;
    float m, l;
};

__device__ __forceinline__ void attn_step(AttnState& st, const KVfrags& kv,
                                          bf16x8 qf0, bf16x8 qf1,
                                          int kb, int qrow0, int lane)
{
    int l15 = lane & 15, quad = lane >> 4;
    f32x4 s0 = {0.f,0.f,0.f,0.f}, s1 = {0.f,0.f,0.f,0.f};
    s0 = __builtin_amdgcn_mfma_f32_16x16x32_bf16(kv.k00, qf0, s0, 0, 0, 0);
    s0 = __builtin_amdgcn_mfma_f32_16x16x32_bf16(kv.k01, qf1, s0, 0, 0, 0);
    s1 = __builtin_amdgcn_mfma_f32_16x16x32_bf16(kv.k10, qf0, s1, 0, 0, 0);
    s1 = __builtin_amdgcn_mfma_f32_16x16x32_bf16(kv.k11, qf1, s1, 0, 0, 0);

    if (kb + 31 > qrow0) {          // wave-uniform: tile straddles diagonal
        int qrow = qrow0 + l15;
        #pragma unroll
        for (int r = 0; r < 4; ++r) {
            int c0 = kb + quad*4 + r;
            if (c0 > qrow)      s0[r] = -1e30f;
            if (c0 + 16 > qrow) s1[r] = -1e30f;
        }
    }

    float tm = fmaxf(fmaxf(fmaxf(s0[0], s0[1]), fmaxf(s0[2], s0[3])),
                     fmaxf(fmaxf(s1[0], s1[1]), fmaxf(s1[2], s1[3])));
    tm = fmaxf(tm, __shfl_xor(tm, 16));
    tm = fmaxf(tm, __shfl_xor(tm, 32));
    float mnew = fmaxf(st.m, tm);
    float alpha = __builtin_amdgcn_exp2f((st.m - mnew) * SM_C);

    float p0[4], p1[4], rs = 0.f;
    #pragma unroll
    for (int r = 0; r < 4; ++r) {
        p0[r] = __builtin_amdgcn_exp2f((s0[r] - mnew) * SM_C);
        p1[r] = __builtin_amdgcn_exp2f((s1[r] - mnew) * SM_C);
        rs += p0[r] + p1[r];
    }
    rs += __shfl_xor(rs, 16);
    rs += __shfl_xor(rs, 32);
    st.l = st.l * alpha + rs;
    st.m = mnew;
    st.o0 *= alpha; st.o1 *= alpha; st.o2 *= alpha; st.o3 *= alpha;

    // P^T -> PV B-frag. Lane (quad,l15) needs k=quad*8+j from source quad'
    // = (quad&1)*2 + (j>>2), array p0 (quad<2) or p1 (quad>=2).
    // ALL shuffles execute unconditionally at full wave exec (a divergent
    // ternary around __shfl reads undefined data from inactive source lanes);
    // the p0/p1 choice is a per-lane v_cndmask on the shuffled results.
    unsigned pk0a = pack2bf(p0[0], p0[1]), pk0b = pack2bf(p0[2], p0[3]);
    unsigned pk1a = pack2bf(p1[0], p1[1]), pk1b = pack2bf(p1[2], p1[3]);
    int sA = l15 + (quad & 1) * 32;
    int sB = sA + 16;
    int hi = quad >> 1;
    unsigned a0A = (unsigned)__shfl((int)pk0a, sA);
    unsigned a1A = (unsigned)__shfl((int)pk1a, sA);
    unsigned b0A = (unsigned)__shfl((int)pk0b, sA);
    unsigned b1A = (unsigned)__shfl((int)pk1b, sA);
    unsigned a0B = (unsigned)__shfl((int)pk0a, sB);
    unsigned a1B = (unsigned)__shfl((int)pk1a, sB);
    unsigned b0B = (unsigned)__shfl((int)pk0b, sB);
    unsigned b1B = (unsigned)__shfl((int)pk1b, sB);
    union { unsigned u[4]; bf16x8 v; } pb;
    pb.u[0] = hi ? a1A : a0A;
    pb.u[1] = hi ? b1A : b0A;
    pb.u[2] = hi ? a1B : a0B;
    pb.u[3] = hi ? b1B : b0B;

    st.o0 = __builtin_amdgcn_mfma_f32_16x16x32_bf16(kv.v0, pb.v, st.o0, 0, 0, 0);
    st.o1 = __builtin_amdgcn_mfma_f32_16x16x32_bf16(kv.v1, pb.v, st.o1, 0, 0, 0);
    st.o2 = __builtin_amdgcn_mfma_f32_16x16x32_bf16(kv.v2, pb.v, st.o2, 0, 0, 0);
    st.o3 = __builtin_amdgcn_mfma_f32_16x16x32_bf16(kv.v3, pb.v, st.o3, 0, 0, 0);
}

// grid: flat 768 blocks (balanced qt triples), 256 threads, wave = 16 Q rows.
__global__ __launch_bounds__(256, 3) void attn_kernel(
    const __bf16* __restrict__ qkv, const __bf16* __restrict__ VT,
    __bf16* __restrict__ ctx)
{
    __shared__ float ot[4][16][68];
    int x = blockIdx.x;
    int region = x >> 8;          // 0,1,2
    int j = x & 255;
    int i = j >> 5;               // 0..7
    int hb = j & 31;
    int qt = (region == 0) ? i : (region == 1) ? (15 - i) : (16 + i);
    int h = hb >> 2, b = hb & 3;

    int tid = threadIdx.x;
    int w = tid >> 6, lane = tid & 63;
    int l15 = lane & 15, quad = lane >> 4;
    int qrow0 = qt * 64 + w * 16;

    const __bf16* qp = qkv + (size_t)(b*SS + qrow0 + l15) * 1536 + h*64 + quad*8;
    bf16x8 qf0 = *(const bf16x8*)qp;
    bf16x8 qf1 = *(const bf16x8*)(qp + 32);

    const __bf16* kp = qkv + (size_t)(b*SS + l15) * 1536 + 512 + h*64 + quad*8;
    const __bf16* vp = VT + ((size_t)(b*NH + h) * 64 + l15) * SS + quad*8;

    AttnState st;
    st.o0 = (f32x4){0.f,0.f,0.f,0.f}; st.o1 = st.o0; st.o2 = st.o0; st.o3 = st.o0;
    st.m = -1e30f; st.l = 0.f;

    int nkt = (qrow0 + 47) >> 5;

    KVfrags ka = load_kv(kp, vp, 0);
    for (int jt = 0; jt < nkt; ) {
        KVfrags kb2;
        bool h1 = (jt + 1) < nkt;
        if (h1) kb2 = load_kv(kp, vp, (jt + 1) * 32);
        attn_step(st, ka, qf0, qf1, jt * 32, qrow0, lane);
        ++jt;
        if (!h1) break;
        if ((jt + 1) < nkt) ka = load_kv(kp, vp, (jt + 1) * 32);
        attn_step(st, kb2, qf0, qf1, jt * 32, qrow0, lane);
        ++jt;
    }

    // epilogue: O^T regs -> LDS -> coalesced bf16 stores
    float inv = 1.f / st.l;
    #pragma unroll
    for (int r = 0; r < 4; ++r) {
        ot[w][l15][ 0 + quad*4 + r] = st.o0[r] * inv;
        ot[w][l15][16 + quad*4 + r] = st.o1[r] * inv;
        ot[w][l15][32 + quad*4 + r] = st.o2[r] * inv;
        ot[w][l15][48 + quad*4 + r] = st.o3[r] * inv;
    }
    asm volatile("s_waitcnt lgkmcnt(0)" ::: "memory");
    int row = lane >> 2, ch = (lane & 3) * 16;
    union { __bf16 hh[16]; uint4 q4[2]; } ob;
    #pragma unroll
    for (int t2 = 0; t2 < 16; ++t2) ob.hh[t2] = f2b(ot[w][row][ch + t2]);
    __bf16* cp = ctx + (size_t)(b*SS + qrow0 + row) * 512 + h*64 + ch;
    *(uint4*)cp = ob.q4[0];
    *(uint4*)(cp + 8) = ob.q4[1];
}

// ================= final projection =================
__global__ __launch_bounds__(256) void proj_kernel(
    const float* __restrict__ h, const float* __restrict__ Wp,
    const float* __restrict__ bp, float* __restrict__ out)
{
    int rid = blockIdx.x * 8 + (threadIdx.x >> 5);
    int col = threadIdx.x & 31;
    int b = rid / TT, i = rid - b * TT;
    const float* x = h + ((size_t)(b*SS) + 3*i + 1) * HDIM;
    float acc = bp[col];
    for (int kk = 0; kk < HDIM; ++kk)
        acc += x[kk] * Wp[kk * ADIM + col];
    out[(size_t)rid * ADIM + col] = acc;
}

extern "C" void kernel_launch(void* const* d_in, const int* in_sizes, int n_in,
                              void* d_out, int out_size, void* d_ws, size_t ws_size,
                              hipStream_t stream)
{
    (void)in_sizes; (void)n_in; (void)out_size; (void)ws_size;
    const int*   timesteps = (const int*)  d_in[0];
    const float* state0    = (const float*)d_in[1];
    const float* state1    = (const float*)d_in[2];
    const float* actions   = (const float*)d_in[3];
    const float* time_emb  = (const float*)d_in[4];
    const float* Ws  = (const float*)d_in[5];
    const float* bs  = (const float*)d_in[6];
    const float* Wa  = (const float*)d_in[7];
    const float* ba  = (const float*)d_in[8];
    const float* Wq  = (const float*)d_in[9];
    const float* bq  = (const float*)d_in[10];
    const float* Wk  = (const float*)d_in[11];
    const float* bk  = (const float*)d_in[12];
    const float* Wv  = (const float*)d_in[13];
    const float* bv  = (const float*)d_in[14];
    const float* Wo  = (const float*)d_in[15];
    const float* bo  = (const float*)d_in[16];
    const float* W1  = (const float*)d_in[17];
    const float* b1  = (const float*)d_in[18];
    const float* W2  = (const float*)d_in[19];
    const float* b2  = (const float*)d_in[20];
    const float* ln1g = (const float*)d_in[21];
    const float* ln1b = (const float*)d_in[22];
    const float* ln2g = (const float*)d_in[23];
    const float* ln2b = (const float*)d_in[24];
    const float* elng = (const float*)d_in[25];
    const float* elnb = (const float*)d_in[26];
    const float* Wp   = (const float*)d_in[27];
    const float* bp   = (const float*)d_in[28];
    float* out = (float*)d_out;

    const size_t SZ = (size_t)MS * HDIM;          // 3,145,728
    char* p = (char*)d_ws;
    float*  h    = (float*)p;            p += SZ * 4;
    float*  tmp  = (float*)p;            p += SZ * 4;
    __bf16* h_bf = (__bf16*)p;           p += SZ * 2;
    __bf16* qkv  = (__bf16*)p;           p += SZ * 3 * 2;
    __bf16* ctx  = (__bf16*)p;           p += SZ * 2;
    __bf16* VT   = (__bf16*)p;           p += SZ * 2;
    __bf16* wqkvT = (__bf16*)p;          p += (size_t)1536 * 512 * 2;
    __bf16* woT   = (__bf16*)p;          p += (size_t)512 * 512 * 2;
    __bf16* w1T   = (__bf16*)p;          p += (size_t)2048 * 512 * 2;
    __bf16* w2T   = (__bf16*)p;          p += (size_t)512 * 2048 * 2;
    float*  biasq = (float*)p;           p += 1536 * 4;
    __bf16* hid  = qkv;                  // MS x DFF bf16, aliases qkv+ctx

    embed_ln_kernel<<<MS, 512, 0, stream>>>(timesteps, state0, state1, actions, time_emb,
                                            Ws, bs, Wa, ba, elng, elnb, h, h_bf);

    dim3 gQKV(1536/128, MS/128);   // 12 x 48
    dim3 gO  (512/128,  MS/128);   // 4 x 48
    dim3 gF1 (2048/128, MS/128);   // 16 x 48
    dim3 gV  (NH, MS/64);          // 8 x 96

    for (int lyr = 0; lyr < NBLK; ++lyr) {
        const float* wq = Wq + (size_t)lyr * HDIM * HDIM;
        const float* wk = Wk + (size_t)lyr * HDIM * HDIM;
        const float* wv = Wv + (size_t)lyr * HDIM * HDIM;
        const float* wo = Wo + (size_t)lyr * HDIM * HDIM;
        const float* w1 = W1 + (size_t)lyr * HDIM * DFF;
        const float* w2 = W2 + (size_t)lyr * DFF * HDIM;

        pack_kernel<<<769, 256, 0, stream>>>(wq, wk, wv, wo, w1, w2,
                                             bq + lyr*HDIM, bk + lyr*HDIM, bv + lyr*HDIM,
                                             wqkvT, woT, w1T, w2T, biasq);
        gemm_mfma<<<gQKV, 256, 0, stream>>>(h_bf, wqkvT, biasq, qkv, MS, 1536, HDIM, 1);
        vtrans_kernel<<<gV, 256, 0, stream>>>(qkv, VT);
        attn_kernel<<<dim3(768), 256, 0, stream>>>(qkv, VT, ctx);
        gemm_mfma<<<gO, 256, 0, stream>>>(ctx, woT, bo + lyr*HDIM, tmp, MS, HDIM, HDIM, 0);
        ln_add_kernel<<<MS, 512, 0, stream>>>(h, tmp, ln1g + lyr*HDIM, ln1b + lyr*HDIM, h_bf);
        gemm_mfma<<<gF1, 256, 0, stream>>>(h_bf, w1T, b1 + lyr*DFF, hid, MS, DFF, HDIM, 1 | 2);
        gemm_mfma<<<gO, 256, 0, stream>>>(hid, w2T, b2 + lyr*HDIM, tmp, MS, HDIM, DFF, 0);
        ln_add_kernel<<<MS, 512, 0, stream>>>(h, tmp, ln2g + lyr*HDIM, ln2b + lyr*HDIM, h_bf);
    }

    proj_kernel<<<(BB*TT)/8, 256, 0, stream>>>(h, Wp, bp, out);
}